// Round 7
// baseline (169.886 us; speedup 1.0000x reference)
//
#include <hip/hip_runtime.h>
#include <math.h>

#define NTGT 512
#define NA 3
#define NCLS 80
#define EPL 7680              // entries per level = 5*3*512
#define OBJ4_TOT 100800       // 403200/4 float4 elements
#define OBJ4_BLOCKS 394       // ceil(100800/256)
#define ENT_BLOCKS 1440       // 23040*16/256
#define CH_PER_LVL 480        // entry chunks per level = EPL*16/256
#define NBLK 1834             // OBJ4_BLOCKS + ENT_BLOCKS
// acc slot layout: slot = q*4 + (b&3), each slot on its own 64B line:
// acc[slot*8]. 13 quantities * 4-way split = 52 slots. Ticket at ws+4096.

__device__ __constant__ float c_anch[3][3][2] = {
  {{10.f,13.f},{16.f,30.f},{33.f,23.f}},
  {{30.f,61.f},{62.f,45.f},{59.f,119.f}},
  {{116.f,90.f},{156.f,198.f},{373.f,326.f}},
};

__device__ inline float sigm(float x){ return 1.0f/(1.0f+expf(-x)); }
__device__ inline float bcel(float x, float z){
  return fmaxf(x,0.0f) - x*z + log1pf(expf(-fabsf(x)));
}
__device__ inline float softp(float x){
  return fmaxf(x,0.f) + log1pf(expf(-fabsf(x)));
}
__device__ inline double wred(double v){
  #pragma unroll
  for(int o=32;o;o>>=1) v += __shfl_down(v,o);
  return v;
}

// Single dispatch. Blocks [0,394): obj softplus (float4). Blocks [394,1834):
// entry domain, 16 threads/entry, lvl block-uniform. Partials published via
// device-scope fp64 atomicAdd into poisoned ws (poison -6e-103 is absorbed).
// Ticket addend depends on the atomic returns -> partials complete before the
// ticket; last block finalizes from 52 coherent slot reads.
__global__ __launch_bounds__(256)
void k_all(const float* __restrict__ p0, const float* __restrict__ p1,
           const float* __restrict__ p2, const float* __restrict__ tg,
           double* __restrict__ acc, unsigned* __restrict__ ticket,
           float* __restrict__ out)
{
  __shared__ double sh[4][4];
  __shared__ double fin[52];
  __shared__ int winflag;

  const int b = blockIdx.x;
  double v0=0.0, v1=0.0, v2=0.0, v3=0.0;   // obj: v0=softplus; entry: box,cls,cnt,objcorr

  if (b < OBJ4_BLOCKS){
    // ---- objectness softplus, float4 (coalesced; vectors never cross planes)
    const int j = b*256 + (int)threadIdx.x;   // float4 index
    if (j < OBJ4_TOT){
      const int i = j*4;
      float4 x; double w;
      if (i < 307200){
        const int bb=i/19200, r=i%19200, a=r/6400, pos=r%6400;
        x = *(const float4*)(p0 + ((long)(bb*255 + a*85 + 4))*6400 + pos);
        w = 4.0/307200.0;
      } else if (i < 384000){
        const int ii=i-307200;
        const int bb=ii/4800, r=ii%4800, a=r/1600, pos=r%1600;
        x = *(const float4*)(p1 + ((long)(bb*255 + a*85 + 4))*1600 + pos);
        w = 1.0/76800.0;
      } else {
        const int ii=i-384000;
        const int bb=ii/1200, r=ii%1200, a=r/400, pos=r%400;
        x = *(const float4*)(p2 + ((long)(bb*255 + a*85 + 4))*400 + pos);
        w = 0.4/19200.0;
      }
      v0 = w * (double)(softp(x.x)+softp(x.y)+softp(x.z)+softp(x.w));
    }
  } else {
    // ---- entry domain: 16 threads per entry ----
    const int ec  = b - OBJ4_BLOCKS;                 // entry chunk [0,1440)
    const int te  = ec*256 + (int)threadIdx.x;       // < 368640
    const int e   = te >> 4;
    const int sub = te & 15;
    const int lvl = ec / CH_PER_LVL;                 // block-uniform
    const int r   = e % EPL;
    const int cc  = r / (NA*NTGT);
    const int a   = (r / NTGT) % NA;
    const int n   = r % NTGT;
    const int W   = 80 >> lvl;
    const float* __restrict__ p = (lvl==0) ? p0 : (lvl==1) ? p1 : p2;

    const float t0 = tg[n*6+0];
    const float t1 = tg[n*6+1];
    const float tx = tg[n*6+2]*(float)W;
    const float ty = tg[n*6+3]*(float)W;
    const float tw = tg[n*6+4]*(float)W;
    const float th = tg[n*6+5]*(float)W;

    const float aw = c_anch[lvl][a][0], ah = c_anch[lvl][a][1];
    const float rw = tw/aw, rh = th/ah;
    const float mr = fmaxf(fmaxf(rw, 1.0f/rw), fmaxf(rh, 1.0f/rh));
    const bool sel = mr < 4.0f;

    const float fx = tx - floorf(tx);
    const float fy = ty - floorf(ty);
    float ox = 0.f, oy = 0.f; bool cond = true;
    if (cc==1){ cond = (fx<0.5f) && (tx>1.0f);               ox =  0.5f; }
    else if (cc==2){ cond = (fy<0.5f) && (ty>1.0f);          oy =  0.5f; }
    else if (cc==3){ cond = (fx>0.5f) && (tx<(float)W-1.0f); ox = -0.5f; }
    else if (cc==4){ cond = (fy>0.5f) && (ty<(float)W-1.0f); oy = -0.5f; }
    const bool valid = sel && cond;

    if (valid){
      const int gridx = (int)(tx - ox);
      const int gridy = (int)(ty - oy);
      const int gx = min(max(gridx,0), W-1);
      const int gy = min(max(gridy,0), W-1);
      const int im = (int)t0;
      const int ci = (int)t1;
      const long long HW = (long long)W*W;
      const long long off = ((long long)(im*255 + a*85)*W + gy)*W + gx;
      const float* base = p + off;

      float cs = 0.f;
      #pragma unroll
      for (int jj=0;jj<5;jj++){
        const int k = sub*5 + jj;
        const float x = base[(long long)(5+k)*HW];
        cs += bcel(x, (k==ci) ? 1.0f : 0.0f);
      }
      v1 = (double)cs;

      if (sub == 0){
        const float gxx = tx - (float)gridx;
        const float gyy = ty - (float)gridy;
        const float o0=base[0], o1=base[HW], o2=base[2*HW], o3=base[3*HW], o4=base[4*HW];
        const float px = sigm(o0)*2.f - 0.5f;
        const float py = sigm(o1)*2.f - 0.5f;
        const float s2 = sigm(o2)*2.f; const float pw = s2*s2*aw;
        const float s3 = sigm(o3)*2.f; const float ph = s3*s3*ah;

        const float ax0=px-pw/2.f, ax1=px+pw/2.f, ay0=py-ph/2.f, ay1=py+ph/2.f;
        const float bx0=gxx-tw/2.f, bx1=gxx+tw/2.f, by0=gyy-th/2.f, by1=gyy+th/2.f;
        const float iw = fmaxf(fminf(ax1,bx1)-fmaxf(ax0,bx0), 0.f);
        const float ih = fmaxf(fminf(ay1,by1)-fmaxf(ay0,by0), 0.f);
        const float inter = iw*ih;
        const float uni = (ax1-ax0)*(ay1-ay0) + (bx1-bx0)*(by1-by0) - inter;
        const float iou = inter/uni;
        const float cwid = fmaxf(ax1,bx1)-fminf(ax0,bx0)+1e-16f;
        const float chei = fmaxf(ay1,by1)-fminf(ay0,by0);
        const float ca = cwid*chei + 1e-16f;
        const float g = iou - (ca-uni)/ca;

        v0 = (double)(1.0f - g);
        v2 = 1.0;
        v3 = -(double)o4 * (double)fmaxf(g, 0.f);  // bce(x,g)-bce(x,0) = -x*g
      }
    }
  }

  // ---- block reduce all 4 sums with a single barrier ----
  v0 = wred(v0); v1 = wred(v1); v2 = wred(v2); v3 = wred(v3);
  if ((threadIdx.x & 63) == 0){
    const int w = threadIdx.x >> 6;
    sh[w][0]=v0; sh[w][1]=v1; sh[w][2]=v2; sh[w][3]=v3;
  }
  __syncthreads();

  if (threadIdx.x == 0){
    const double S0 = sh[0][0]+sh[1][0]+sh[2][0]+sh[3][0];
    const double S1 = sh[0][1]+sh[1][1]+sh[2][1]+sh[3][1];
    const double S2 = sh[0][2]+sh[1][2]+sh[2][2]+sh[3][2];
    const double S3 = sh[0][3]+sh[1][3]+sh[2][3]+sh[3][3];
    const int j = b & 3;
    double guard;
    if (b < OBJ4_BLOCKS){
      guard = atomicAdd(&acc[(12*4 + j)*8], S0);
    } else {
      const int lvl = (b - OBJ4_BLOCKS) / CH_PER_LVL;
      const double o0 = atomicAdd(&acc[((lvl*4+0)*4 + j)*8], S0);
      const double o1 = atomicAdd(&acc[((lvl*4+1)*4 + j)*8], S1);
      const double o2 = atomicAdd(&acc[((lvl*4+2)*4 + j)*8], S2);
      const double o3 = atomicAdd(&acc[((lvl*4+3)*4 + j)*8], S3);
      guard = o0+o1+o2+o3;
    }
    // ok==1 always, but data-depends on the atomic returns: the partial RMWs
    // are complete at the coherence point before the ticket increments.
    const unsigned ok = (guard != guard) ? 0u : 1u;
    const unsigned old = __hip_atomic_fetch_add(ticket, ok, __ATOMIC_RELAXED,
                                                __HIP_MEMORY_SCOPE_AGENT);
    winflag = (old == 0xAAAAAAAAu + (unsigned)(NBLK-1)) ||
              (old == (unsigned)(NBLK-1));
  }
  __syncthreads();
  if (!winflag) return;

  // ---- winner: gather the 52 slots (coherent reads) and finalize ----
  if (threadIdx.x < 52){
    fin[threadIdx.x] = __hip_atomic_load(&acc[threadIdx.x*8], __ATOMIC_RELAXED,
                                         __HIP_MEMORY_SCOPE_AGENT);
  }
  __syncthreads();
  if (threadIdx.x == 0){
    double S[13];
    #pragma unroll
    for (int q=0;q<13;q++)
      S[q] = fin[q*4+0]+fin[q*4+1]+fin[q*4+2]+fin[q*4+3];

    double lbox = 0.0, lcls = 0.0;
    double lobj = S[12];
    const double bal[3] = {4.0, 1.0, 0.4};
    const double sz[3]  = {307200.0, 76800.0, 19200.0};
    for (int l=0; l<3; l++){
      const double cnt = S[l*4+2];
      const double den = cnt > 1.0 ? cnt : 1.0;
      if (cnt > 0.0){
        lbox += S[l*4+0] / den;
        lcls += S[l*4+1] / (den * 80.0);
      }
      lobj += bal[l] * S[l*4+3] / sz[l];
    }
    const double loss = (0.05*lbox + 1.0*lobj + 0.5*lcls) * 16.0;
    out[0] = (float)loss;
  }
}

extern "C" void kernel_launch(void* const* d_in, const int* in_sizes, int n_in,
                              void* d_out, int out_size, void* d_ws, size_t ws_size,
                              hipStream_t stream)
{
  const float* p0 = (const float*)d_in[0];
  const float* p1 = (const float*)d_in[1];
  const float* p2 = (const float*)d_in[2];
  const float* tg = (const float*)d_in[3];
  double* acc = (double*)d_ws;
  unsigned* ticket = (unsigned*)((char*)d_ws + 4096);

  k_all<<<NBLK, 256, 0, stream>>>(p0, p1, p2, tg, acc, ticket, (float*)d_out);
}

// Round 8
// 164.220 us; speedup vs baseline: 1.0345x; 1.0345x over previous
//
#include <hip/hip_runtime.h>
#include <math.h>

#define NTGT 512
#define NA 3
#define NCLS 80
#define EPL 7680              // entries per level = 5*3*512
#define OBJ4_TOT 100800       // 403200/4 float4 elements
#define OBJ4_BLOCKS 394       // ceil(100800/256)
#define ENT_BLOCKS 1440       // 23040*16/256
#define CH_PER_LVL 480        // entry chunks per level = EPL*16/256
#define NBLK 1834             // OBJ4_BLOCKS + ENT_BLOCKS
#define PST 2048              // partials stride: part[q*PST + block]

__device__ __constant__ float c_anch[3][3][2] = {
  {{10.f,13.f},{16.f,30.f},{33.f,23.f}},
  {{30.f,61.f},{62.f,45.f},{59.f,119.f}},
  {{116.f,90.f},{156.f,198.f},{373.f,326.f}},
};

__device__ inline float sigm(float x){ return 1.0f/(1.0f+expf(-x)); }
__device__ inline float bcel(float x, float z){
  return fmaxf(x,0.0f) - x*z + log1pf(expf(-fabsf(x)));
}
__device__ inline float softp(float x){
  return fmaxf(x,0.f) + log1pf(expf(-fabsf(x)));
}
__device__ inline double wred(double v){
  #pragma unroll
  for(int o=32;o;o>>=1) v += __shfl_down(v,o);
  return v;
}
// Block reduce (256 threads). All threads call; result valid in all threads.
__device__ inline double bred(double v, double* sh){
  v = wred(v);
  __syncthreads();
  if ((threadIdx.x & 63) == 0) sh[threadIdx.x>>6] = v;
  __syncthreads();
  return sh[0]+sh[1]+sh[2]+sh[3];
}

// One chunk per block. Blocks [0,394): obj softplus (float4). Blocks
// [394,1834): entry domain, 16 threads/entry; lvl is block-uniform.
// Each block publishes ONLY its own partials (plain stores; kernel boundary
// provides coherence): obj -> part[12*PST+b]; entry lvl l -> part[(l*4+s)*PST+b].
__global__ __launch_bounds__(256)
void k_main(const float* __restrict__ p0, const float* __restrict__ p1,
            const float* __restrict__ p2, const float* __restrict__ tg,
            double* __restrict__ part)
{
  __shared__ double sh[4];
  const int b = blockIdx.x;

  if (b < OBJ4_BLOCKS){
    // ---- objectness softplus, float4 (coalesced; vectors never cross planes)
    const int j = b*256 + (int)threadIdx.x;   // float4 index
    double s = 0.0;
    if (j < OBJ4_TOT){
      const int i = j*4;
      float4 x; double w;
      if (i < 307200){
        const int bb=i/19200, r=i%19200, a=r/6400, pos=r%6400;
        x = *(const float4*)(p0 + ((long)(bb*255 + a*85 + 4))*6400 + pos);
        w = 4.0/307200.0;
      } else if (i < 384000){
        const int ii=i-307200;
        const int bb=ii/4800, r=ii%4800, a=r/1600, pos=r%1600;
        x = *(const float4*)(p1 + ((long)(bb*255 + a*85 + 4))*1600 + pos);
        w = 1.0/76800.0;
      } else {
        const int ii=i-384000;
        const int bb=ii/1200, r=ii%1200, a=r/400, pos=r%400;
        x = *(const float4*)(p2 + ((long)(bb*255 + a*85 + 4))*400 + pos);
        w = 0.4/19200.0;
      }
      s = w * (double)(softp(x.x)+softp(x.y)+softp(x.z)+softp(x.w));
    }
    s = bred(s, sh);
    if (threadIdx.x == 0) part[12*PST + b] = s;
  } else {
    // ---- entry domain: 16 threads per entry ----
    const int ec  = b - OBJ4_BLOCKS;                 // entry chunk [0,1440)
    const int te  = ec*256 + (int)threadIdx.x;       // < 368640
    const int e   = te >> 4;
    const int sub = te & 15;
    const int lvl = ec / CH_PER_LVL;                 // block-uniform
    const int r   = e % EPL;
    const int cc  = r / (NA*NTGT);
    const int a   = (r / NTGT) % NA;
    const int n   = r % NTGT;
    const int W   = 80 >> lvl;
    const float* __restrict__ p = (lvl==0) ? p0 : (lvl==1) ? p1 : p2;

    const float t0 = tg[n*6+0];
    const float t1 = tg[n*6+1];
    const float tx = tg[n*6+2]*(float)W;
    const float ty = tg[n*6+3]*(float)W;
    const float tw = tg[n*6+4]*(float)W;
    const float th = tg[n*6+5]*(float)W;

    const float aw = c_anch[lvl][a][0], ah = c_anch[lvl][a][1];
    const float rw = tw/aw, rh = th/ah;
    const float mr = fmaxf(fmaxf(rw, 1.0f/rw), fmaxf(rh, 1.0f/rh));
    const bool sel = mr < 4.0f;

    const float fx = tx - floorf(tx);
    const float fy = ty - floorf(ty);
    float ox = 0.f, oy = 0.f; bool cond = true;
    if (cc==1){ cond = (fx<0.5f) && (tx>1.0f);               ox =  0.5f; }
    else if (cc==2){ cond = (fy<0.5f) && (ty>1.0f);          oy =  0.5f; }
    else if (cc==3){ cond = (fx>0.5f) && (tx<(float)W-1.0f); ox = -0.5f; }
    else if (cc==4){ cond = (fy>0.5f) && (ty<(float)W-1.0f); oy = -0.5f; }
    const bool valid = sel && cond;

    double vbox=0.0, vcnt=0.0, vobj=0.0, vcls=0.0;
    if (valid){
      const int gridx = (int)(tx - ox);
      const int gridy = (int)(ty - oy);
      const int gx = min(max(gridx,0), W-1);
      const int gy = min(max(gridy,0), W-1);
      const int im = (int)t0;
      const int ci = (int)t1;
      const long long HW = (long long)W*W;
      const long long off = ((long long)(im*255 + a*85)*W + gy)*W + gx;
      const float* base = p + off;

      float cs = 0.f;
      #pragma unroll
      for (int jj=0;jj<5;jj++){
        const int k = sub*5 + jj;
        const float x = base[(long long)(5+k)*HW];
        cs += bcel(x, (k==ci) ? 1.0f : 0.0f);
      }
      vcls = (double)cs;

      if (sub == 0){
        const float gxx = tx - (float)gridx;
        const float gyy = ty - (float)gridy;
        const float o0=base[0], o1=base[HW], o2=base[2*HW], o3=base[3*HW], o4=base[4*HW];
        const float px = sigm(o0)*2.f - 0.5f;
        const float py = sigm(o1)*2.f - 0.5f;
        const float s2 = sigm(o2)*2.f; const float pw = s2*s2*aw;
        const float s3 = sigm(o3)*2.f; const float ph = s3*s3*ah;

        const float ax0=px-pw/2.f, ax1=px+pw/2.f, ay0=py-ph/2.f, ay1=py+ph/2.f;
        const float bx0=gxx-tw/2.f, bx1=gxx+tw/2.f, by0=gyy-th/2.f, by1=gyy+th/2.f;
        const float iw = fmaxf(fminf(ax1,bx1)-fmaxf(ax0,bx0), 0.f);
        const float ih = fmaxf(fminf(ay1,by1)-fmaxf(ay0,by0), 0.f);
        const float inter = iw*ih;
        const float uni = (ax1-ax0)*(ay1-ay0) + (bx1-bx0)*(by1-by0) - inter;
        const float iou = inter/uni;
        const float cwid = fmaxf(ax1,bx1)-fminf(ax0,bx0)+1e-16f;
        const float chei = fmaxf(ay1,by1)-fminf(ay0,by0);
        const float ca = cwid*chei + 1e-16f;
        const float g = iou - (ca-uni)/ca;

        vbox = (double)(1.0f - g);
        vcnt = 1.0;
        vobj = -(double)o4 * (double)fmaxf(g, 0.f);  // bce(x,g)-bce(x,0) = -x*g
      }
    }

    double rv;
    rv = bred(vbox, sh); if (threadIdx.x==0) part[(lvl*4+0)*PST + b] = rv;
    rv = bred(vcls, sh); if (threadIdx.x==0) part[(lvl*4+1)*PST + b] = rv;
    rv = bred(vcnt, sh); if (threadIdx.x==0) part[(lvl*4+2)*PST + b] = rv;
    rv = bred(vobj, sh); if (threadIdx.x==0) part[(lvl*4+3)*PST + b] = rv;
  }
}

__global__ __launch_bounds__(256)
void k_final(const double* __restrict__ part, float* __restrict__ out)
{
  __shared__ double sh[4];
  // Gather all per-thread sums first (independent, coalesced loads), reading
  // ONLY published slots: q=12 from blocks [0,394); q=l*4+s from the lvl-l
  // entry block range [394+480l, 394+480(l+1)).
  double t[13];
  #pragma unroll
  for (int q=0;q<13;q++) t[q]=0.0;
  for (int i = threadIdx.x; i < OBJ4_BLOCKS; i += 256)
    t[12] += part[12*PST + i];
  #pragma unroll
  for (int l=0;l<3;l++){
    const int base = OBJ4_BLOCKS + l*CH_PER_LVL;
    for (int i = threadIdx.x; i < CH_PER_LVL; i += 256){
      #pragma unroll
      for (int s=0;s<4;s++)
        t[l*4+s] += part[(l*4+s)*PST + base + i];
    }
  }
  double S[13];
  #pragma unroll
  for (int q=0;q<13;q++) S[q] = bred(t[q], sh);

  if (threadIdx.x == 0){
    double lbox = 0.0, lcls = 0.0;
    double lobj = S[12];
    const double bal[3] = {4.0, 1.0, 0.4};
    const double sz[3]  = {307200.0, 76800.0, 19200.0};
    for (int l=0; l<3; l++){
      const double cnt = S[l*4+2];
      const double den = cnt > 1.0 ? cnt : 1.0;
      if (cnt > 0.0){
        lbox += S[l*4+0] / den;
        lcls += S[l*4+1] / (den * 80.0);
      }
      lobj += bal[l] * S[l*4+3] / sz[l];
    }
    const double loss = (0.05*lbox + 1.0*lobj + 0.5*lcls) * 16.0;
    out[0] = (float)loss;
  }
}

extern "C" void kernel_launch(void* const* d_in, const int* in_sizes, int n_in,
                              void* d_out, int out_size, void* d_ws, size_t ws_size,
                              hipStream_t stream)
{
  const float* p0 = (const float*)d_in[0];
  const float* p1 = (const float*)d_in[1];
  const float* p2 = (const float*)d_in[2];
  const float* tg = (const float*)d_in[3];
  double* part = (double*)d_ws;

  k_main<<<NBLK, 256, 0, stream>>>(p0, p1, p2, tg, part);
  k_final<<<1, 256, 0, stream>>>(part, (float*)d_out);
}